// Round 4
// baseline (225.323 us; speedup 1.0000x reference)
//
#include <hip/hip_runtime.h>
#include <stdint.h>

typedef unsigned int uint32;

#define BB 64
#define CC 256
#define OO 256
#define HH 28
#define WW 28
#define HWP 784           // 28*28
#define NWT 589824        // 256*256*9

// conv slab: 12 rows x 30 cols x 8 words, zero-padded borders
#define SROWS 12
#define SCOLS 30
#define SLAB_DW (SROWS * SCOLS * 8)  // 2880 dwords = 11520 B

// ---------------------------------------------------------------------------
// Kernel 1: binarize & bit-pack activations.
// apack[b][p][j] (j=0..7): bit (c%32) of word j=c/32 set iff x[b][c][p] > 0.
// ---------------------------------------------------------------------------
__global__ __launch_bounds__(256) void pack_x_kernel(
    const float* __restrict__ x, uint32* __restrict__ apack) {
  int p = blockIdx.x * 256 + threadIdx.x;
  int j = blockIdx.y;
  int b = blockIdx.z;
  if (p >= HWP) return;
  const float* xp = x + ((size_t)(b * CC + j * 32) * HWP) + p;
  uint32 m = 0;
#pragma unroll
  for (int cc = 0; cc < 32; ++cc) {
    float v = xp[(size_t)cc * HWP];
    m |= ((uint32)(v > 0.0f)) << cc;
  }
  apack[((size_t)b * HWP + p) * 8 + j] = m;
}

// ---------------------------------------------------------------------------
// Kernel 2: binarize & bit-pack weights (coalesced, LDS-staged).
// sign(w) = sign(m + rv.z) since the rsqrt normalizer is positive.
// wpack[o][tap][j]: tap = (dh+1)*3 + (dw+1), j = c/32, bit = c%32.
// ---------------------------------------------------------------------------
__global__ __launch_bounds__(256) void pack_w_kernel(
    const float* __restrict__ M, const float* __restrict__ Z,
    const float* __restrict__ rv, uint32* __restrict__ wpack) {
  __shared__ float sacc[576];
  const int o = blockIdx.x;
  const int jh = blockIdx.y;  // 0..3 -> words j = jh*2, jh*2+1
  const int tid = threadIdx.x;
  const size_t base = (size_t)o * 2304 + (size_t)jh * 576;

  float r[8];
#pragma unroll
  for (int k = 0; k < 8; ++k) r[k] = rv[k];

#pragma unroll
  for (int ii = 0; ii < 3; ++ii) {
    int i = tid + ii * 256;
    if (i < 576) {
      float s = M[base + i];
#pragma unroll
      for (int k = 0; k < 8; ++k) s += r[k] * Z[(size_t)k * NWT + base + i];
      sacc[i] = s;
    }
  }
  __syncthreads();

  if (tid < 18) {
    int tap = tid % 9;
    int jj = tid / 9;
    uint32 m = 0;
#pragma unroll
    for (int cc = 0; cc < 32; ++cc) {
      float v = sacc[(jj * 32 + cc) * 9 + tap];
      m |= ((uint32)(v > 0.0f)) << cc;
    }
    wpack[(o * 9 + tap) * 8 + jh * 2 + jj] = m;
  }
}

// ---------------------------------------------------------------------------
// Kernel 2b: per-o parameter table for the border-class affine correction.
// For invalid (zero-padded) taps the xor-popcount sees a=0 bits and counts
// popc(w_t); algebra: out = alpha*(256*nv_cls - 2*(total - Sum_inv popc(w_t)))
//                        = A[o][cls] + m[o]*total,
// A[o][cls] = alpha*(256*nv_cls + 2*S_cls), m[o] = -2*alpha.
// cls = hclass*3 + wclass (0=lo-edge,1=interior,2=hi-edge).
// ---------------------------------------------------------------------------
__global__ __launch_bounds__(256) void ptab_kernel(
    const uint32* __restrict__ wpack, const float* __restrict__ alpha,
    float* __restrict__ ptabA, float* __restrict__ ptabM) {
  int o = threadIdx.x;  // single block of 256
  const uint32* wt = wpack + (size_t)o * 72;
  int pt[9];
#pragma unroll
  for (int t = 0; t < 9; ++t) {
    int s = 0;
#pragma unroll
    for (int j = 0; j < 8; ++j) s += __popc(wt[t * 8 + j]);
    pt[t] = s;
  }
  int row0 = pt[0] + pt[1] + pt[2], row2 = pt[6] + pt[7] + pt[8];
  int col0 = pt[0] + pt[3] + pt[6], col2 = pt[2] + pt[5] + pt[8];
  float a = alpha[o];
  const int nv[9] = {4, 6, 4, 6, 9, 6, 4, 6, 4};
  int S[9];
  S[0] = row0 + col0 - pt[0]; S[1] = row0; S[2] = row0 + col2 - pt[2];
  S[3] = col0;                S[4] = 0;    S[5] = col2;
  S[6] = row2 + col0 - pt[6]; S[7] = row2; S[8] = row2 + col2 - pt[8];
#pragma unroll
  for (int c = 0; c < 9; ++c)
    ptabA[o * 9 + c] = a * (float)(256 * nv[c] + 2 * S[c]);
  ptabM[o] = -2.0f * a;
}

// ---------------------------------------------------------------------------
// Kernel 3: binary conv, weight-in-SGPR / activation-in-LDS structure.
// Block = (pixel tile of 256, o-group of 64, b). Lane = flat pixel p;
// wave loops over o. Weight address is readfirstlane-pinned uniform ->
// s_load; the 18 tap reads are ds_read_b128 off ONE lane address with
// compile-time immediate offsets (zero-padded 30-col slab). Inner loop:
// v_xor_b32 v,s,v + v_bcnt_u32_b32 accumulate = 2 VALU/word (floor).
// Border pixels handled exactly via the ptab affine correction.
// ---------------------------------------------------------------------------
__global__ __launch_bounds__(256, 4) void conv_kernel(
    const uint32* __restrict__ apack, const uint32* __restrict__ wpack,
    const float* __restrict__ ptabA, const float* __restrict__ ptabM,
    float* __restrict__ out) {
  __shared__ uint32 slab[SLAB_DW];  // 11520 B, zero-padded act tile
  __shared__ float atab[64 * 9];    // 2304 B, A[o_local][cls]

  const int tile = blockIdx.x;  // 0..3   (256-pixel tile; tile 3 is rump)
  const int og = blockIdx.y;    // 0..3   (64 output channels)
  const int b = blockIdx.z;     // 0..63
  const int tid = threadIdx.x;

  const int p0 = tile * 256;
  const int r0 = (p0 / 28) - 1;  // first slab row (may be -1)

  // Stage A table (64 o x 9 classes).
  for (int i = tid; i < 576; i += 256) atab[i] = ptabA[og * 576 + i];

  // Zero the slab (borders + out-of-image rows stay zero).
  for (int i = tid; i < SLAB_DW / 4; i += 256)
    ((uint4*)slab)[i] = make_uint4(0, 0, 0, 0);
  __syncthreads();

  // Copy in-image rows: 12 rows x 28 px x 32B = 672 16B-items.
  for (int q = tid; q < 672; q += 256) {
    int row = q / 56;        // slab row
    int c16 = q - row * 56;  // 16B item within row (56 per row)
    int r = r0 + row;
    if (r >= 0 && r < HH) {
      const uint4* src =
          (const uint4*)(apack + ((size_t)(b * HWP + r * WW) * 8)) + c16;
      ((uint4*)slab)[(row * SCOLS + 1) * 2 + c16] = *src;
    }
  }
  __syncthreads();

  // Whole-wave early exit for the rump tile (post-barrier: safe).
  if (p0 + (tid & ~63) >= HWP) return;

  const int p = p0 + tid;
  const bool active = p < HWP;
  const int h = p / 28;
  const int w = p - h * 28;
  const int hc = (h == 0) ? 0 : (h == 27 ? 2 : 1);
  const int wc = (w == 0) ? 0 : (w == 27 ? 2 : 1);
  const int cls = hc * 3 + wc;
  // byte address of tap (dh=-1,dw=-1) for this lane
  const int abase = ((h - r0 - 1) * SCOLS + w) * 32;
  const char* sbase = (const char*)slab + abase;

  const size_t outbase = ((size_t)b * OO + og * 64) * HWP + p;

  for (int oi = 0; oi < 64; ++oi) {
    const int o = og * 64 + oi;
    // Pin the weight offset to an SGPR so the 72-dword weight block is
    // s_load'ed (wave-uniform), not vector-loaded per lane.
    const int wo = __builtin_amdgcn_readfirstlane(o * 72);
    const uint32* wt = wpack + wo;
    const float m = ptabM[o];  // uniform -> s_load

    int total = 0;
#pragma unroll
    for (int dh = 0; dh < 3; ++dh) {
#pragma unroll
      for (int dw = 0; dw < 3; ++dw) {
        const uint4* sp = (const uint4*)(sbase + (dh * SCOLS + dw) * 32);
        uint4 a0 = sp[0];
        uint4 a1 = sp[1];
        const uint32* wtt = wt + (dh * 3 + dw) * 8;
        total += __popc(a0.x ^ wtt[0]) + __popc(a0.y ^ wtt[1]) +
                 __popc(a0.z ^ wtt[2]) + __popc(a0.w ^ wtt[3]) +
                 __popc(a1.x ^ wtt[4]) + __popc(a1.y ^ wtt[5]) +
                 __popc(a1.z ^ wtt[6]) + __popc(a1.w ^ wtt[7]);
      }
    }
    float res = fmaf(m, (float)total, atab[oi * 9 + cls]);
    if (active) out[outbase + (size_t)oi * HWP] = res;
  }
}

// ---------------------------------------------------------------------------
extern "C" void kernel_launch(void* const* d_in, const int* in_sizes, int n_in,
                              void* d_out, int out_size, void* d_ws,
                              size_t ws_size, hipStream_t stream) {
  const float* x     = (const float*)d_in[0];  // (64,256,28,28)
  const float* M     = (const float*)d_in[1];  // (256,256,3,3)
  const float* Z     = (const float*)d_in[2];  // (8,256,256,3,3)
  const float* alpha = (const float*)d_in[3];  // (256,1,1)
  const float* rv    = (const float*)d_in[4];  // (1,8)
  float* out = (float*)d_out;                  // (64,256,28,28)

  uint32* apack = (uint32*)d_ws;                         // 1,605,632 B
  uint32* wpack = (uint32*)((char*)d_ws + 1605632);      // 73,728 B
  float* ptabA  = (float*)((char*)d_ws + 1679360);       // 9,216 B
  float* ptabM  = (float*)((char*)d_ws + 1688576);       // 1,024 B

  pack_x_kernel<<<dim3(4, 8, BB), 256, 0, stream>>>(x, apack);
  pack_w_kernel<<<dim3(256, 4), 256, 0, stream>>>(M, Z, rv, wpack);
  ptab_kernel<<<dim3(1), 256, 0, stream>>>(wpack, alpha, ptabA, ptabM);
  conv_kernel<<<dim3(4, 4, BB), 256, 0, stream>>>(apack, wpack, ptabA, ptabM,
                                                  out);
}

// Round 5
// 204.280 us; speedup vs baseline: 1.1030x; 1.1030x over previous
//
#include <hip/hip_runtime.h>
#include <stdint.h>

typedef unsigned int uint32;

#define BB 64
#define CC 256
#define OO 256
#define HH 28
#define WW 28
#define HWP 784           // 28*28
#define NWT 589824        // 256*256*9

// ---------------------------------------------------------------------------
// Kernel 1: binarize & bit-pack activations.
// apack[b][p][j] (j=0..7): bit (c%32) of word j=c/32 set iff x[b][c][p] > 0.
// ---------------------------------------------------------------------------
__global__ __launch_bounds__(256) void pack_x_kernel(
    const float* __restrict__ x, uint32* __restrict__ apack) {
  int p = blockIdx.x * 256 + threadIdx.x;
  int j = blockIdx.y;
  int b = blockIdx.z;
  if (p >= HWP) return;
  const float* xp = x + ((size_t)(b * CC + j * 32) * HWP) + p;
  uint32 m = 0;
#pragma unroll
  for (int cc = 0; cc < 32; ++cc) {
    float v = xp[(size_t)cc * HWP];
    m |= ((uint32)(v > 0.0f)) << cc;
  }
  apack[((size_t)b * HWP + p) * 8 + j] = m;
}

// ---------------------------------------------------------------------------
// Kernel 2: binarize & bit-pack weights (coalesced, LDS-staged).
// sign(w) = sign(m + rv.z) since the rsqrt normalizer is positive.
// wpack[o][tap][j]: tap = (dh+1)*3 + (dw+1), j = c/32, bit = c%32.
// ---------------------------------------------------------------------------
__global__ __launch_bounds__(256) void pack_w_kernel(
    const float* __restrict__ M, const float* __restrict__ Z,
    const float* __restrict__ rv, uint32* __restrict__ wpack) {
  __shared__ float sacc[576];
  const int o = blockIdx.x;
  const int jh = blockIdx.y;  // 0..3 -> words j = jh*2, jh*2+1
  const int tid = threadIdx.x;
  const size_t base = (size_t)o * 2304 + (size_t)jh * 576;

  float r[8];
#pragma unroll
  for (int k = 0; k < 8; ++k) r[k] = rv[k];

#pragma unroll
  for (int ii = 0; ii < 3; ++ii) {
    int i = tid + ii * 256;
    if (i < 576) {
      float s = M[base + i];
#pragma unroll
      for (int k = 0; k < 8; ++k) s += r[k] * Z[(size_t)k * NWT + base + i];
      sacc[i] = s;
    }
  }
  __syncthreads();

  if (tid < 18) {
    int tap = tid % 9;
    int jj = tid / 9;
    uint32 m = 0;
#pragma unroll
    for (int cc = 0; cc < 32; ++cc) {
      float v = sacc[(jj * 32 + cc) * 9 + tap];
      m |= ((uint32)(v > 0.0f)) << cc;
    }
    wpack[(o * 9 + tap) * 8 + jh * 2 + jj] = m;
  }
}

// ---------------------------------------------------------------------------
// Kernel 2b: per-o tables.
// ptabA[o][cls] = alpha*(256*nv_cls + 2*S_cls)  (affine border correction:
//   every invalid tap's xor-with-zero contributes popc(w_t); verified R4).
// ptabP[o] = {m = -2*alpha (as bits), col0, col2, 0} where
//   col0 = sum_dh popc(w[dh][dw=-1]), col2 = sum_dh popc(w[dh][dw=+1])
//   (the "virtual zero column" totals used at the w edges).
// ---------------------------------------------------------------------------
__global__ __launch_bounds__(256) void ptab_kernel(
    const uint32* __restrict__ wpack, const float* __restrict__ alpha,
    float* __restrict__ ptabA, uint32* __restrict__ ptabP) {
  int o = threadIdx.x;  // single block of 256
  const uint32* wt = wpack + (size_t)o * 72;
  int pt[9];
#pragma unroll
  for (int t = 0; t < 9; ++t) {
    int s = 0;
#pragma unroll
    for (int j = 0; j < 8; ++j) s += __popc(wt[t * 8 + j]);
    pt[t] = s;
  }
  int row0 = pt[0] + pt[1] + pt[2], row2 = pt[6] + pt[7] + pt[8];
  int col0 = pt[0] + pt[3] + pt[6], col2 = pt[2] + pt[5] + pt[8];
  float a = alpha[o];
  const int nv[9] = {4, 6, 4, 6, 9, 6, 4, 6, 4};
  int S[9];
  S[0] = row0 + col0 - pt[0]; S[1] = row0; S[2] = row0 + col2 - pt[2];
  S[3] = col0;                S[4] = 0;    S[5] = col2;
  S[6] = row2 + col0 - pt[6]; S[7] = row2; S[8] = row2 + col2 - pt[8];
#pragma unroll
  for (int c = 0; c < 9; ++c)
    ptabA[o * 9 + c] = a * (float)(256 * nv[c] + 2 * S[c]);
  ptabP[o * 4 + 0] = __float_as_uint(-2.0f * a);
  ptabP[o * 4 + 1] = (uint32)col0;
  ptabP[o * 4 + 2] = (uint32)col2;
  ptabP[o * 4 + 3] = 0;
}

// ---------------------------------------------------------------------------
// Kernel 3: binary conv — weights in SGPRs, activations in VGPRs.
// Lane = pixel (w = lane&31, 2 rows per wave); wave loops over 64 o.
// Per o (uniform): 72 weight dwords via s_load; inner op is
// v_xor_b32 v,s,v + v_bcnt_u32_b32 accumulate into 3 column sums T[dw].
// Horizontal mix: T from lane w-1 / w+1 via 1-lane shuffles; w-edges
// substitute the per-o virtual-zero-column constants col0/col2, making
// `total` bit-identical to the R4 zero-padded-slab total -> same ptab
// affine epilogue (absmax 0.5, verified). No weight RA fight (scalar
// file), no per-o LDS traffic (R4's 22.4M bank-conflict cycles -> ~0).
// ---------------------------------------------------------------------------
__global__ __launch_bounds__(128) void conv_kernel(
    const uint32* __restrict__ apack, const uint32* __restrict__ wpack,
    const float* __restrict__ ptabA, const uint32* __restrict__ ptabP,
    float* __restrict__ out) {
  __shared__ float atab[64 * 9];  // A[o_local][cls]

  const int rg = blockIdx.x;   // 0..6  (4 rows per block)
  const int og = blockIdx.y;   // 0..3  (64 o per block)
  const int b  = blockIdx.z;   // 0..63
  const int tid = threadIdx.x; // 128 = 2 waves; each wave covers 2 rows
  const int w = tid & 31;
  const int r = rg * 4 + (tid >> 5);
  const bool active = w < WW;

  for (int i = tid; i < 576; i += 128) atab[i] = ptabA[og * 576 + i];
  __syncthreads();

  // Own-column activations, rows r-1..r+1, zero-padded out of image.
  const int wcl = active ? w : (WW - 1);  // clamp inactive lanes in-bounds
  uint4 A[3][2];
#pragma unroll
  for (int dh = 0; dh < 3; ++dh) {
    int rr = r + dh - 1;
    bool v = (rr >= 0) && (rr < HH);
    int rrc = v ? rr : 0;
    const uint4* src =
        (const uint4*)(apack + ((size_t)(b * HWP + rrc * WW + wcl)) * 8);
    uint4 lo = src[0], hi = src[1];
    if (!v) { lo = make_uint4(0, 0, 0, 0); hi = make_uint4(0, 0, 0, 0); }
    A[dh][0] = lo;
    A[dh][1] = hi;
  }

  const int hc = (r == 0) ? 0 : (r == HH - 1 ? 2 : 1);
  const int wc = (w == 0) ? 0 : (w == WW - 1 ? 2 : 1);
  const int cls = hc * 3 + wc;

  const size_t obase = ((size_t)b * OO + og * 64) * HWP + r * WW + w;

  for (int oi = 0; oi < 64; ++oi) {
    const int o = og * 64 + oi;
    const int wo = __builtin_amdgcn_readfirstlane(o * 72);
    const uint32* wt = wpack + wo;                    // uniform -> s_load
    const uint4 pm = ((const uint4*)ptabP)[o];        // uniform -> s_load
    const float m = __uint_as_float(pm.x);

    int T0 = 0, T1 = 0, T2 = 0;
#pragma unroll
    for (int dh = 0; dh < 3; ++dh) {
      const uint32* a = (const uint32*)&A[dh][0];
#pragma unroll
      for (int j = 0; j < 8; ++j) {
        uint32 av = a[j];
        T0 += __popc(av ^ wt[(dh * 3 + 0) * 8 + j]);
        T1 += __popc(av ^ wt[(dh * 3 + 1) * 8 + j]);
        T2 += __popc(av ^ wt[(dh * 3 + 2) * 8 + j]);
      }
    }
    int tl = __shfl_up(T0, 1);    // column sum from lane w-1
    int tr = __shfl_down(T2, 1);  // column sum from lane w+1
    if (w == 0) tl = (int)pm.y;         // virtual zero column (col0)
    if (w == WW - 1) tr = (int)pm.z;    // virtual zero column (col2)
    int total = tl + T1 + tr;
    float res = fmaf(m, (float)total, atab[oi * 9 + cls]);
    if (active) out[obase + (size_t)oi * HWP] = res;
  }
}

// ---------------------------------------------------------------------------
extern "C" void kernel_launch(void* const* d_in, const int* in_sizes, int n_in,
                              void* d_out, int out_size, void* d_ws,
                              size_t ws_size, hipStream_t stream) {
  const float* x     = (const float*)d_in[0];  // (64,256,28,28)
  const float* M     = (const float*)d_in[1];  // (256,256,3,3)
  const float* Z     = (const float*)d_in[2];  // (8,256,256,3,3)
  const float* alpha = (const float*)d_in[3];  // (256,1,1)
  const float* rv    = (const float*)d_in[4];  // (1,8)
  float* out = (float*)d_out;                  // (64,256,28,28)

  uint32* apack = (uint32*)d_ws;                         // 1,605,632 B
  uint32* wpack = (uint32*)((char*)d_ws + 1605632);      // 73,728 B
  float*  ptabA = (float*)((char*)d_ws + 1679360);       // 9,216 B
  uint32* ptabP = (uint32*)((char*)d_ws + 1688576);      // 4,096 B

  pack_x_kernel<<<dim3(4, 8, BB), 256, 0, stream>>>(x, apack);
  pack_w_kernel<<<dim3(256, 4), 256, 0, stream>>>(M, Z, rv, wpack);
  ptab_kernel<<<dim3(1), 256, 0, stream>>>(wpack, alpha, ptabA, ptabP);
  conv_kernel<<<dim3(7, 4, BB), 128, 0, stream>>>(apack, wpack, ptabA, ptabP,
                                                  out);
}

// Round 6
// 192.054 us; speedup vs baseline: 1.1732x; 1.0637x over previous
//
#include <hip/hip_runtime.h>
#include <stdint.h>

typedef unsigned int uint32;

#define BB 64
#define CC 256
#define OO 256
#define HH 28
#define WW 28
#define HWP 784           // 28*28
#define NWT 589824        // 256*256*9

// ---------------------------------------------------------------------------
// Kernel 1: binarize & bit-pack activations.
// apack[b][p][j] (j=0..7): bit (c%32) of word j=c/32 set iff x[b][c][p] > 0.
// ---------------------------------------------------------------------------
__global__ __launch_bounds__(256) void pack_x_kernel(
    const float* __restrict__ x, uint32* __restrict__ apack) {
  int p = blockIdx.x * 256 + threadIdx.x;
  int j = blockIdx.y;
  int b = blockIdx.z;
  if (p >= HWP) return;
  const float* xp = x + ((size_t)(b * CC + j * 32) * HWP) + p;
  uint32 m = 0;
#pragma unroll
  for (int cc = 0; cc < 32; ++cc) {
    float v = xp[(size_t)cc * HWP];
    m |= ((uint32)(v > 0.0f)) << cc;
  }
  apack[((size_t)b * HWP + p) * 8 + j] = m;
}

// ---------------------------------------------------------------------------
// Kernel 2: binarize & bit-pack weights (coalesced, LDS-staged).
// sign(w) = sign(m + rv.z) since the rsqrt normalizer is positive.
// wpack[o][tap][j]: tap = (dh+1)*3 + (dw+1), j = c/32, bit = c%32.
// ---------------------------------------------------------------------------
__global__ __launch_bounds__(256) void pack_w_kernel(
    const float* __restrict__ M, const float* __restrict__ Z,
    const float* __restrict__ rv, uint32* __restrict__ wpack) {
  __shared__ float sacc[576];
  const int o = blockIdx.x;
  const int jh = blockIdx.y;  // 0..3 -> words j = jh*2, jh*2+1
  const int tid = threadIdx.x;
  const size_t base = (size_t)o * 2304 + (size_t)jh * 576;

  float r[8];
#pragma unroll
  for (int k = 0; k < 8; ++k) r[k] = rv[k];

#pragma unroll
  for (int ii = 0; ii < 3; ++ii) {
    int i = tid + ii * 256;
    if (i < 576) {
      float s = M[base + i];
#pragma unroll
      for (int k = 0; k < 8; ++k) s += r[k] * Z[(size_t)k * NWT + base + i];
      sacc[i] = s;
    }
  }
  __syncthreads();

  if (tid < 18) {
    int tap = tid % 9;
    int jj = tid / 9;
    uint32 m = 0;
#pragma unroll
    for (int cc = 0; cc < 32; ++cc) {
      float v = sacc[(jj * 32 + cc) * 9 + tap];
      m |= ((uint32)(v > 0.0f)) << cc;
    }
    wpack[(o * 9 + tap) * 8 + jh * 2 + jj] = m;
  }
}

// ---------------------------------------------------------------------------
// Kernel 2b: per-o tables (affine border correction, verified R4/R5).
// ptabA[o][cls] = alpha*(256*nv_cls + 2*S_cls); cls = hclass*3 + wclass.
// ptabP[o] = {-2*alpha (bits), col0, col2, 0}: virtual zero-column popcounts.
// ---------------------------------------------------------------------------
__global__ __launch_bounds__(256) void ptab_kernel(
    const uint32* __restrict__ wpack, const float* __restrict__ alpha,
    float* __restrict__ ptabA, uint32* __restrict__ ptabP) {
  int o = threadIdx.x;  // single block of 256
  const uint32* wt = wpack + (size_t)o * 72;
  int pt[9];
#pragma unroll
  for (int t = 0; t < 9; ++t) {
    int s = 0;
#pragma unroll
    for (int j = 0; j < 8; ++j) s += __popc(wt[t * 8 + j]);
    pt[t] = s;
  }
  int row0 = pt[0] + pt[1] + pt[2], row2 = pt[6] + pt[7] + pt[8];
  int col0 = pt[0] + pt[3] + pt[6], col2 = pt[2] + pt[5] + pt[8];
  float a = alpha[o];
  const int nv[9] = {4, 6, 4, 6, 9, 6, 4, 6, 4};
  int S[9];
  S[0] = row0 + col0 - pt[0]; S[1] = row0; S[2] = row0 + col2 - pt[2];
  S[3] = col0;                S[4] = 0;    S[5] = col2;
  S[6] = row2 + col0 - pt[6]; S[7] = row2; S[8] = row2 + col2 - pt[8];
#pragma unroll
  for (int c = 0; c < 9; ++c)
    ptabA[o * 9 + c] = a * (float)(256 * nv[c] + 2 * S[c]);
  ptabP[o * 4 + 0] = __float_as_uint(-2.0f * a);
  ptabP[o * 4 + 1] = (uint32)col0;
  ptabP[o * 4 + 2] = (uint32)col2;
  ptabP[o * 4 + 3] = 0;
}

// ---------------------------------------------------------------------------
// Kernel 3 (v3): binary conv — weights in SGPRs, activations in VGPRs,
// 2 output rows per lane, 16 o per block, full wave-slot grid.
// R5 post-mortem: only 3584 waves (30% occupancy) -> per-o s_load waits
// and popc dep chains unhidden (VALUBusy 58%). v3: 8192 waves
// (grid 2x16x64 blocks of 4 waves, bounds(256,6)), 6 independent popc
// accumulator chains per o, weight words loop-uniform -> scalar file.
// Algebra identical to R5 (absmax 0.5 verified): T[k][dw] are 3-row
// column popcount sums (zero-padded rows), horizontal mix via 1-lane
// shuffles with virtual-zero-column constants at w edges, ptab affine
// epilogue for the padding correction.
// ---------------------------------------------------------------------------
__global__ __launch_bounds__(256, 6) void conv_kernel(
    const uint32* __restrict__ apack, const uint32* __restrict__ wpack,
    const float* __restrict__ ptabA, const uint32* __restrict__ ptabP,
    float* __restrict__ out) {
  __shared__ float atab[16 * 9];  // A[o_local][cls]

  const int rg = blockIdx.x;   // 0..1  (16 rows)
  const int og = blockIdx.y;   // 0..15 (16 o)
  const int b  = blockIdx.z;   // 0..63
  const int tid = threadIdx.x;
  const int lane = tid & 63;
  const int wv = tid >> 6;                       // wave 0..3
  const int w = lane & 31;
  const int rb = rg * 16 + wv * 4 + (lane >> 5) * 2;  // first of 2 out rows
  const bool wact = w < WW;

  if (tid < 144) atab[tid] = ptabA[og * 144 + tid];
  __syncthreads();

  // Own-column activations, rows rb-1 .. rb+2 (zero-padded outside image).
  const int wcl = wact ? w : (WW - 1);
  uint4 A[4][2];
#pragma unroll
  for (int i = 0; i < 4; ++i) {
    int rr = rb - 1 + i;
    bool v = (rr >= 0) && (rr < HH);
    const uint4* src =
        (const uint4*)(apack + ((size_t)(b * HWP + (v ? rr : 0) * WW + wcl)) * 8);
    uint4 lo = src[0], hi = src[1];
    if (!v) { lo = make_uint4(0, 0, 0, 0); hi = make_uint4(0, 0, 0, 0); }
    A[i][0] = lo;
    A[i][1] = hi;
  }

  const int wc = (w == 0) ? 0 : (w == WW - 1 ? 2 : 1);
  const int r1v = rb + 1;
  const int hc0 = (rb == 0) ? 0 : (rb == HH - 1 ? 2 : 1);
  const int hc1 = (r1v == 0) ? 0 : (r1v == HH - 1 ? 2 : 1);
  const int cls0 = hc0 * 3 + wc;
  const int cls1 = hc1 * 3 + wc;

  const size_t obase = ((size_t)b * OO + og * 16) * HWP + (size_t)rb * WW + w;
  const bool st0 = wact && (rb < HH);
  const bool st1 = wact && (r1v < HH);

  for (int oi = 0; oi < 16; ++oi) {
    const int o = og * 16 + oi;
    const int wo = __builtin_amdgcn_readfirstlane(o * 72);
    const uint32* wt = wpack + wo;                // uniform -> s_load
    const uint4 pm = ((const uint4*)ptabP)[o];    // uniform -> s_load
    const float m = __uint_as_float(pm.x);

    // 6 independent popcount accumulator chains (ILP).
    int T00 = 0, T01 = 0, T02 = 0, T10 = 0, T11 = 0, T12 = 0;
#pragma unroll
    for (int dh = 0; dh < 3; ++dh) {
      const uint32* a0 = (const uint32*)&A[dh][0];      // output row rb
      const uint32* a1 = (const uint32*)&A[dh + 1][0];  // output row rb+1
#pragma unroll
      for (int j = 0; j < 8; ++j) {
        const uint32 w0 = wt[(dh * 3 + 0) * 8 + j];
        const uint32 w1 = wt[(dh * 3 + 1) * 8 + j];
        const uint32 w2 = wt[(dh * 3 + 2) * 8 + j];
        const uint32 av0 = a0[j], av1 = a1[j];
        T00 += __popc(av0 ^ w0); T01 += __popc(av0 ^ w1); T02 += __popc(av0 ^ w2);
        T10 += __popc(av1 ^ w0); T11 += __popc(av1 ^ w1); T12 += __popc(av1 ^ w2);
      }
    }
    int tl0 = __shfl_up(T00, 1), tr0 = __shfl_down(T02, 1);
    int tl1 = __shfl_up(T10, 1), tr1 = __shfl_down(T12, 1);
    if (w == 0)      { tl0 = (int)pm.y; tl1 = (int)pm.y; }
    if (w == WW - 1) { tr0 = (int)pm.z; tr1 = (int)pm.z; }
    float r0 = fmaf(m, (float)(tl0 + T01 + tr0), atab[oi * 9 + cls0]);
    float r1 = fmaf(m, (float)(tl1 + T11 + tr1), atab[oi * 9 + cls1]);
    if (st0) out[obase + (size_t)oi * HWP] = r0;
    if (st1) out[obase + (size_t)oi * HWP + WW] = r1;
  }
}

// ---------------------------------------------------------------------------
extern "C" void kernel_launch(void* const* d_in, const int* in_sizes, int n_in,
                              void* d_out, int out_size, void* d_ws,
                              size_t ws_size, hipStream_t stream) {
  const float* x     = (const float*)d_in[0];  // (64,256,28,28)
  const float* M     = (const float*)d_in[1];  // (256,256,3,3)
  const float* Z     = (const float*)d_in[2];  // (8,256,256,3,3)
  const float* alpha = (const float*)d_in[3];  // (256,1,1)
  const float* rv    = (const float*)d_in[4];  // (1,8)
  float* out = (float*)d_out;                  // (64,256,28,28)

  uint32* apack = (uint32*)d_ws;                         // 1,605,632 B
  uint32* wpack = (uint32*)((char*)d_ws + 1605632);      // 73,728 B
  float*  ptabA = (float*)((char*)d_ws + 1679360);       // 9,216 B
  uint32* ptabP = (uint32*)((char*)d_ws + 1688576);      // 4,096 B

  pack_x_kernel<<<dim3(4, 8, BB), 256, 0, stream>>>(x, apack);
  pack_w_kernel<<<dim3(256, 4), 256, 0, stream>>>(M, Z, rv, wpack);
  ptab_kernel<<<dim3(1), 256, 0, stream>>>(wpack, alpha, ptabA, ptabP);
  conv_kernel<<<dim3(2, 16, BB), 256, 0, stream>>>(apack, wpack, ptabA, ptabP,
                                                   out);
}

// Round 7
// 191.178 us; speedup vs baseline: 1.1786x; 1.0046x over previous
//
#include <hip/hip_runtime.h>
#include <stdint.h>

typedef unsigned int uint32;

#define BB 64
#define CC 256
#define OO 256
#define HH 28
#define WW 28
#define HWP 784           // 28*28
#define NWT 589824        // 256*256*9

// ---------------------------------------------------------------------------
// Kernel 1: binarize & bit-pack activations.
// apack[b][p][j] (j=0..7): bit (c%32) of word j=c/32 set iff x[b][c][p] > 0.
// ---------------------------------------------------------------------------
__global__ __launch_bounds__(256) void pack_x_kernel(
    const float* __restrict__ x, uint32* __restrict__ apack) {
  int p = blockIdx.x * 256 + threadIdx.x;
  int j = blockIdx.y;
  int b = blockIdx.z;
  if (p >= HWP) return;
  const float* xp = x + ((size_t)(b * CC + j * 32) * HWP) + p;
  uint32 m = 0;
#pragma unroll
  for (int cc = 0; cc < 32; ++cc) {
    float v = xp[(size_t)cc * HWP];
    m |= ((uint32)(v > 0.0f)) << cc;
  }
  apack[((size_t)b * HWP + p) * 8 + j] = m;
}

// ---------------------------------------------------------------------------
// Kernel 2: binarize & bit-pack weights (coalesced, LDS-staged).
// sign(w) = sign(m + rv.z) since the rsqrt normalizer is positive.
// wpack[o][tap][j]: tap = (dh+1)*3 + (dw+1), j = c/32, bit = c%32.
// ---------------------------------------------------------------------------
__global__ __launch_bounds__(256) void pack_w_kernel(
    const float* __restrict__ M, const float* __restrict__ Z,
    const float* __restrict__ rv, uint32* __restrict__ wpack) {
  __shared__ float sacc[576];
  const int o = blockIdx.x;
  const int jh = blockIdx.y;  // 0..3 -> words j = jh*2, jh*2+1
  const int tid = threadIdx.x;
  const size_t base = (size_t)o * 2304 + (size_t)jh * 576;

  float r[8];
#pragma unroll
  for (int k = 0; k < 8; ++k) r[k] = rv[k];

#pragma unroll
  for (int ii = 0; ii < 3; ++ii) {
    int i = tid + ii * 256;
    if (i < 576) {
      float s = M[base + i];
#pragma unroll
      for (int k = 0; k < 8; ++k) s += r[k] * Z[(size_t)k * NWT + base + i];
      sacc[i] = s;
    }
  }
  __syncthreads();

  if (tid < 18) {
    int tap = tid % 9;
    int jj = tid / 9;
    uint32 m = 0;
#pragma unroll
    for (int cc = 0; cc < 32; ++cc) {
      float v = sacc[(jj * 32 + cc) * 9 + tap];
      m |= ((uint32)(v > 0.0f)) << cc;
    }
    wpack[(o * 9 + tap) * 8 + jh * 2 + jj] = m;
  }
}

// ---------------------------------------------------------------------------
// Kernel 2b: per-o tables (affine border correction, verified R4-R6).
// ptabA[o][cls] = alpha*(256*nv_cls + 2*S_cls); cls = hclass*3 + wclass.
// ptabP[o] = {-2*alpha (bits), col0, col2, 0}: virtual zero-column popcounts.
// ---------------------------------------------------------------------------
__global__ __launch_bounds__(256) void ptab_kernel(
    const uint32* __restrict__ wpack, const float* __restrict__ alpha,
    float* __restrict__ ptabA, uint32* __restrict__ ptabP) {
  int o = threadIdx.x;  // single block of 256
  const uint32* wt = wpack + (size_t)o * 72;
  int pt[9];
#pragma unroll
  for (int t = 0; t < 9; ++t) {
    int s = 0;
#pragma unroll
    for (int j = 0; j < 8; ++j) s += __popc(wt[t * 8 + j]);
    pt[t] = s;
  }
  int row0 = pt[0] + pt[1] + pt[2], row2 = pt[6] + pt[7] + pt[8];
  int col0 = pt[0] + pt[3] + pt[6], col2 = pt[2] + pt[5] + pt[8];
  float a = alpha[o];
  const int nv[9] = {4, 6, 4, 6, 9, 6, 4, 6, 4};
  int S[9];
  S[0] = row0 + col0 - pt[0]; S[1] = row0; S[2] = row0 + col2 - pt[2];
  S[3] = col0;                S[4] = 0;    S[5] = col2;
  S[6] = row2 + col0 - pt[6]; S[7] = row2; S[8] = row2 + col2 - pt[8];
#pragma unroll
  for (int c = 0; c < 9; ++c)
    ptabA[o * 9 + c] = a * (float)(256 * nv[c] + 2 * S[c]);
  ptabP[o * 4 + 0] = __float_as_uint(-2.0f * a);
  ptabP[o * 4 + 1] = (uint32)col0;
  ptabP[o * 4 + 2] = (uint32)col2;
  ptabP[o * 4 + 3] = 0;
}

// Guaranteed fused popcount-accumulate: T = bitcount(x) + T, one VALU inst.
// (R6 post-mortem: measured VALU inst count ~1.9x the 2-ops/word model,
// consistent with the compiler emitting bcnt(x,0) + separate v_add.)
#define BCNT_ACC(T, x) asm("v_bcnt_u32_b32 %0, %1, %0" : "+v"(T) : "v"(x))

// ---------------------------------------------------------------------------
// Kernel 3 (v4): binary conv — weights in SGPRs, activations in VGPRs,
// 2 output rows per lane, 16 o per block, 8 blocks/CU exactly resident
// (launch_bounds(256,8); VGPR was 36 so the 64 cap fits).
// Core inner op pinned to 2 VALU/word-pair via BCNT_ACC. Horizontal mix
// uses ONE packed shuffle per direction (row0 in low16, row1 in high16;
// column sums <= 768 so the packed add is carry-free). Algebra identical
// to R5/R6 (absmax 0.5 verified): ptab affine epilogue corrects the
// zero-padding; w-edges substitute virtual-zero-column constants.
// ---------------------------------------------------------------------------
__global__ __launch_bounds__(256, 8) void conv_kernel(
    const uint32* __restrict__ apack, const uint32* __restrict__ wpack,
    const float* __restrict__ ptabA, const uint32* __restrict__ ptabP,
    float* __restrict__ out) {
  __shared__ float atab[16 * 9];  // A[o_local][cls]

  const int rg = blockIdx.x;   // 0..1  (16 rows)
  const int og = blockIdx.y;   // 0..15 (16 o)
  const int b  = blockIdx.z;   // 0..63
  const int tid = threadIdx.x;
  const int lane = tid & 63;
  const int wv = tid >> 6;                       // wave 0..3
  const int w = lane & 31;
  const int rb = rg * 16 + wv * 4 + (lane >> 5) * 2;  // first of 2 out rows
  const bool wact = w < WW;

  if (tid < 144) atab[tid] = ptabA[og * 144 + tid];
  __syncthreads();

  // Own-column activations, rows rb-1 .. rb+2 (zero-padded outside image).
  const int wcl = wact ? w : (WW - 1);
  uint4 A[4][2];
#pragma unroll
  for (int i = 0; i < 4; ++i) {
    int rr = rb - 1 + i;
    bool v = (rr >= 0) && (rr < HH);
    const uint4* src =
        (const uint4*)(apack + ((size_t)(b * HWP + (v ? rr : 0) * WW + wcl)) * 8);
    uint4 lo = src[0], hi = src[1];
    if (!v) { lo = make_uint4(0, 0, 0, 0); hi = make_uint4(0, 0, 0, 0); }
    A[i][0] = lo;
    A[i][1] = hi;
  }

  const int wc = (w == 0) ? 0 : (w == WW - 1 ? 2 : 1);
  const int r1v = rb + 1;
  const int hc0 = (rb == 0) ? 0 : (rb == HH - 1 ? 2 : 1);
  const int hc1 = (r1v == 0) ? 0 : (r1v == HH - 1 ? 2 : 1);
  const int cls0 = hc0 * 3 + wc;
  const int cls1 = hc1 * 3 + wc;

  const size_t obase = ((size_t)b * OO + og * 16) * HWP + (size_t)rb * WW + w;
  const bool st0 = wact && (rb < HH);
  const bool st1 = wact && (r1v < HH);

  for (int oi = 0; oi < 16; ++oi) {
    const int o = og * 16 + oi;
    const int wo = __builtin_amdgcn_readfirstlane(o * 72);
    const uint32* wt = wpack + wo;                // uniform -> s_load
    const uint4 pm = ((const uint4*)ptabP)[o];    // uniform -> s_load
    const float m = __uint_as_float(pm.x);

    // 6 independent fused popcount chains (ILP), 2 VALU per word-pair.
    uint32 T00 = 0, T01 = 0, T02 = 0, T10 = 0, T11 = 0, T12 = 0;
#pragma unroll
    for (int dh = 0; dh < 3; ++dh) {
      const uint32* a0 = (const uint32*)&A[dh][0];      // output row rb
      const uint32* a1 = (const uint32*)&A[dh + 1][0];  // output row rb+1
#pragma unroll
      for (int j = 0; j < 8; ++j) {
        const uint32 w0 = wt[(dh * 3 + 0) * 8 + j];
        const uint32 w1 = wt[(dh * 3 + 1) * 8 + j];
        const uint32 w2 = wt[(dh * 3 + 2) * 8 + j];
        const uint32 av0 = a0[j], av1 = a1[j];
        BCNT_ACC(T00, av0 ^ w0);
        BCNT_ACC(T01, av0 ^ w1);
        BCNT_ACC(T02, av0 ^ w2);
        BCNT_ACC(T10, av1 ^ w0);
        BCNT_ACC(T11, av1 ^ w1);
        BCNT_ACC(T12, av1 ^ w2);
      }
    }
    // Packed horizontal mix: row0 in low 16, row1 in high 16 (sums <= 768).
    uint32 pl = __shfl_up(T00 | (T10 << 16), 1);
    uint32 pr = __shfl_down(T02 | (T12 << 16), 1);
    if (w == 0)      pl = pm.y * 0x10001u;  // virtual zero column col0
    if (w == WW - 1) pr = pm.z * 0x10001u;  // virtual zero column col2
    uint32 tp = pl + (T01 | (T11 << 16)) + pr;  // carry-free packed add
    float r0 = fmaf(m, (float)(tp & 0xffffu), atab[oi * 9 + cls0]);
    float r1 = fmaf(m, (float)(tp >> 16), atab[oi * 9 + cls1]);
    if (st0) out[obase + (size_t)oi * HWP] = r0;
    if (st1) out[obase + (size_t)oi * HWP + WW] = r1;
  }
}

// ---------------------------------------------------------------------------
extern "C" void kernel_launch(void* const* d_in, const int* in_sizes, int n_in,
                              void* d_out, int out_size, void* d_ws,
                              size_t ws_size, hipStream_t stream) {
  const float* x     = (const float*)d_in[0];  // (64,256,28,28)
  const float* M     = (const float*)d_in[1];  // (256,256,3,3)
  const float* Z     = (const float*)d_in[2];  // (8,256,256,3,3)
  const float* alpha = (const float*)d_in[3];  // (256,1,1)
  const float* rv    = (const float*)d_in[4];  // (1,8)
  float* out = (float*)d_out;                  // (64,256,28,28)

  uint32* apack = (uint32*)d_ws;                         // 1,605,632 B
  uint32* wpack = (uint32*)((char*)d_ws + 1605632);      // 73,728 B
  float*  ptabA = (float*)((char*)d_ws + 1679360);       // 9,216 B
  uint32* ptabP = (uint32*)((char*)d_ws + 1688576);      // 4,096 B

  pack_x_kernel<<<dim3(4, 8, BB), 256, 0, stream>>>(x, apack);
  pack_w_kernel<<<dim3(256, 4), 256, 0, stream>>>(M, Z, rv, wpack);
  ptab_kernel<<<dim3(1), 256, 0, stream>>>(wpack, alpha, ptabA, ptabP);
  conv_kernel<<<dim3(2, 16, BB), 256, 0, stream>>>(apack, wpack, ptabA, ptabP,
                                                   out);
}